// Round 5
// baseline (67.290 us; speedup 1.0000x reference)
//
#include <hip/hip_runtime.h>

#define Bc 8
#define Nc 360
#define Dc 128
#define LDST 132   // LDS row stride (floats); measured 0 bank conflicts r1-r3

typedef float f32x4 __attribute__((ext_vector_type(4)));

// Force a (known wave-uniform) pointer into SGPRs so "s" asm constraints are satisfiable.
__device__ __forceinline__ const float* uptr(const float* p) {
    unsigned long long v = (unsigned long long)p;
    unsigned lo = __builtin_amdgcn_readfirstlane((unsigned)(v & 0xffffffffu));
    unsigned hi = __builtin_amdgcn_readfirstlane((unsigned)(v >> 32));
    return (const float*)((((unsigned long long)hi) << 32) | lo);
}

// 8 consecutive W1 rows (stride 2*Dc*4 = 0x400 bytes), 16B each, via scalar pipe.
__device__ __forceinline__ void sload_w8(const float* base,
    f32x4& A0, f32x4& A1, f32x4& A2, f32x4& A3,
    f32x4& A4, f32x4& A5, f32x4& A6, f32x4& A7)
{
    asm volatile(
        "s_load_dwordx4 %0, %8, 0x0\n\t"
        "s_load_dwordx4 %1, %8, 0x400\n\t"
        "s_load_dwordx4 %2, %8, 0x800\n\t"
        "s_load_dwordx4 %3, %8, 0xc00\n\t"
        "s_load_dwordx4 %4, %8, 0x1000\n\t"
        "s_load_dwordx4 %5, %8, 0x1400\n\t"
        "s_load_dwordx4 %6, %8, 0x1800\n\t"
        "s_load_dwordx4 %7, %8, 0x1c00\n\t"
        "s_waitcnt lgkmcnt(0)"
        : "=&s"(A0), "=&s"(A1), "=&s"(A2), "=&s"(A3),
          "=&s"(A4), "=&s"(A5), "=&s"(A6), "=&s"(A7)
        : "s"(base)
        : "memory");
}

// 6 consecutive Av rows (stride Dc*4 = 0x200 bytes) + 16B of sign vector.
__device__ __forceinline__ void sload_a6s(const float* abase, const float* sbase,
    f32x4& A0, f32x4& A1, f32x4& A2, f32x4& A3, f32x4& A4, f32x4& A5, f32x4& Sv)
{
    asm volatile(
        "s_load_dwordx4 %0, %7, 0x0\n\t"
        "s_load_dwordx4 %1, %7, 0x200\n\t"
        "s_load_dwordx4 %2, %7, 0x400\n\t"
        "s_load_dwordx4 %3, %7, 0x600\n\t"
        "s_load_dwordx4 %4, %7, 0x800\n\t"
        "s_load_dwordx4 %5, %7, 0xa00\n\t"
        "s_load_dwordx4 %6, %8, 0x0\n\t"
        "s_waitcnt lgkmcnt(0)"
        : "=&s"(A0), "=&s"(A1), "=&s"(A2), "=&s"(A3), "=&s"(A4), "=&s"(A5), "=&s"(Sv)
        : "s"(abase), "s"(sbase)
        : "memory");
}

// proj: Bv[row,c] = w2_c * ( emb[row,:] . W1[c, 0:128] )              (sender,  j side)
//       Av[row,c] = w2_c * ( emb[row,:] . W1[c, 128:256] + b1[c] )    (receiver, i side)
// Also: rsB[row] += sum_c Bv[row,c]; rsA[row] += sum_c Av[row,c]  (atomic, memset'd to 0)
__global__ __launch_bounds__(256) void proj_kernel(
    const float* __restrict__ emb, const float* __restrict__ W1,
    const float* __restrict__ b1, const float* __restrict__ W2,
    float* __restrict__ Av, float* __restrict__ Bv, float* __restrict__ s_arr,
    float* __restrict__ rsA, float* __restrict__ rsB)
{
    __shared__ float E_s[64 * LDST];
    const int t  = threadIdx.x;
    const int r0 = blockIdx.x * 64;

    if (blockIdx.x == 0 && blockIdx.y == 0 && t < Dc)
        s_arr[t] = copysignf(0.5f, W2[t]);

    {
        const int rsub = t >> 5, c4 = (t & 31) * 4;
        #pragma unroll
        for (int p = 0; p < 8; ++p) {
            const int r = p * 8 + rsub;
            *(float4*)&E_s[r * LDST + c4] = *(const float4*)&emb[(r0 + r) * Dc + c4];
        }
    }
    __syncthreads();

    const int lane = t & 63;
    const int wu   = __builtin_amdgcn_readfirstlane(t >> 6);   // wave 0..3
    const int c0   = blockIdx.y * 32 + wu * 8;                 // uniform, 0..255
    const bool recv = (c0 >= Dc);
    const int  cl   = recv ? (c0 - Dc) : c0;                   // uniform local col base
    const float* wbase = uptr(W1 + cl * (2 * Dc) + (recv ? Dc : 0));

    float acc[8];
    #pragma unroll
    for (int cc = 0; cc < 8; ++cc) acc[cc] = 0.0f;

    #pragma unroll
    for (int k4 = 0; k4 < 32; ++k4) {
        f32x4 Wv[8];
        sload_w8(wbase, Wv[0], Wv[1], Wv[2], Wv[3], Wv[4], Wv[5], Wv[6], Wv[7]);
        const f32x4 ev = *(const f32x4*)&E_s[lane * LDST + k4 * 4];
        #pragma unroll
        for (int cc = 0; cc < 8; ++cc) {
            acc[cc] = fmaf(Wv[cc][0], ev[0], acc[cc]);
            acc[cc] = fmaf(Wv[cc][1], ev[1], acc[cc]);
            acc[cc] = fmaf(Wv[cc][2], ev[2], acc[cc]);
            acc[cc] = fmaf(Wv[cc][3], ev[3], acc[cc]);
        }
        wbase += 4;
    }

    #pragma unroll
    for (int cc = 0; cc < 8; ++cc) {
        float v = recv ? (acc[cc] + b1[cl + cc]) : acc[cc];
        acc[cc] = v * W2[cl + cc];
    }
    float* dst = (recv ? Av : Bv) + (r0 + lane) * Dc + cl;
    *(float4*)(dst + 0) = make_float4(acc[0], acc[1], acc[2], acc[3]);
    *(float4*)(dst + 4) = make_float4(acc[4], acc[5], acc[6], acc[7]);

    const float sum8 = ((acc[0] + acc[1]) + (acc[2] + acc[3]))
                     + ((acc[4] + acc[5]) + (acc[6] + acc[7]));
    atomicAdd((recv ? rsA : rsB) + (r0 + lane), sum8);
}

// edge: out[b,i,j] = relu( b2 + 0.5*(rsA[i]+rsB[j]) + sum_d s_d*|Av[i,d]+Bv[j,d]| )
// Block: 64 j (lane, LDS-staged Bv rows) x 24 i (6/wave via scalar-pipe loads). Grid 6x15x8.
__global__ __launch_bounds__(256) void edge_kernel(
    const float* __restrict__ Av, const float* __restrict__ Bv,
    const float* __restrict__ s_arr, const float* __restrict__ b2,
    const float* __restrict__ rsA, const float* __restrict__ rsB,
    float* __restrict__ out)
{
    __shared__ float B_s[64 * LDST];
    const int t  = threadIdx.x;
    const int b  = blockIdx.z;
    const int j0 = blockIdx.x * 64;
    const int i0 = blockIdx.y * 24;    // 360 = 15*24, no i tail

    {
        const int rsub = t >> 5, c4 = (t & 31) * 4;
        #pragma unroll
        for (int p = 0; p < 8; ++p) {
            const int r = p * 8 + rsub;
            int jr = j0 + r; if (jr > Nc - 1) jr = Nc - 1;
            *(float4*)&B_s[r * LDST + c4] = *(const float4*)&Bv[(b * Nc + jr) * Dc + c4];
        }
    }
    __syncthreads();

    const int lane = t & 63;
    const int wu   = __builtin_amdgcn_readfirstlane(t >> 6);   // wave 0..3
    const int ia   = i0 + wu * 6;                              // uniform
    const float* ap = uptr(Av + (b * Nc + ia) * Dc);
    const float* sp = uptr(s_arr);

    float acc[6];
    #pragma unroll
    for (int q = 0; q < 6; ++q) acc[q] = 0.0f;

    #pragma unroll
    for (int k4 = 0; k4 < 32; ++k4) {
        f32x4 A[6], Sv;
        sload_a6s(ap, sp, A[0], A[1], A[2], A[3], A[4], A[5], Sv);
        const f32x4 bv = *(const f32x4*)&B_s[lane * LDST + k4 * 4];
        #pragma unroll
        for (int e = 0; e < 4; ++e) {
            const float se = Sv[e];
            const float be = bv[e];
            #pragma unroll
            for (int q = 0; q < 6; ++q) {
                const float tq = A[q][e] + be;              // 1 SGPR operand
                acc[q] = fmaf(se, fabsf(tq), acc[q]);       // |.| = free modifier
            }
        }
        ap += 4; sp += 4;
    }

    const int jg = j0 + lane;
    const int jc = jg > Nc - 1 ? Nc - 1 : jg;
    const float sigj = rsB[b * Nc + jc];
    if (jg < Nc) {
        const float bb = b2[0];
        #pragma unroll
        for (int q = 0; q < 6; ++q) {
            const float rho = rsA[b * Nc + ia + q];
            out[(b * Nc + ia + q) * Nc + jg] =
                fmaxf(fmaf(0.5f, rho + sigj, acc[q]) + bb, 0.0f);
        }
    }
}

extern "C" void kernel_launch(void* const* d_in, const int* in_sizes, int n_in,
                              void* d_out, int out_size, void* d_ws, size_t ws_size,
                              hipStream_t stream) {
    const float* emb = (const float*)d_in[0];   // [B,N,D]
    const float* W1  = (const float*)d_in[1];   // [D, 2D]
    const float* b1  = (const float*)d_in[2];   // [D]
    const float* W2  = (const float*)d_in[3];   // [1, D]
    const float* b2  = (const float*)d_in[4];   // [1]
    float* out = (float*)d_out;                 // [B,N,N,1]

    float* Av    = (float*)d_ws;                // [2880,128] w2-scaled receiver proj (+b1)
    float* Bv    = Av + Bc * Nc * Dc;           // [2880,128] w2-scaled sender proj
    float* s_arr = Bv + Bc * Nc * Dc;           // [128] 0.5*sgn(w2)
    float* rsA   = s_arr + Dc;                  // [2880] row sums of Av
    float* rsB   = rsA + Bc * Nc;               // [2880] row sums of Bv

    hipMemsetAsync(rsA, 0, 2 * Bc * Nc * sizeof(float), stream);
    proj_kernel<<<dim3(Bc * Nc / 64, 8), 256, 0, stream>>>(emb, W1, b1, W2, Av, Bv, s_arr, rsA, rsB);
    edge_kernel<<<dim3(6, 15, Bc), 256, 0, stream>>>(Av, Bv, s_arr, b2, rsA, rsB, out);
}